// Round 1
// baseline (87.440 us; speedup 1.0000x reference)
//
#include <hip/hip_runtime.h>
#include <stdint.h>

#define HH 2048
#define WW 2048
#define NPIX (HH * WW)
#define WPR (WW / 32)   // 64 words per row

// distinct squared distances in the 9x9 window (sorted ascending)
__device__ __constant__ int c_d2s[14] = {1, 2, 4, 5, 8, 9, 10, 13, 16, 17, 18, 20, 25, 32};

__host__ __device__ constexpr int g_of(int d2) {
  switch (d2) {
    case 1:  return 0;  case 2:  return 1;  case 4:  return 2;  case 5:  return 3;
    case 8:  return 4;  case 9:  return 5;  case 10: return 6;  case 13: return 7;
    case 16: return 8;  case 17: return 9;  case 18: return 10; case 20: return 11;
    case 25: return 12; case 32: return 13;
  }
  return 15;
}

// ---------------- K0: init min/max ----------------
__global__ void k_init(unsigned* minmax) {
  minmax[0] = 0x7f800000u;  // +inf (min accumulator)
  minmax[1] = 0u;           // 0    (max accumulator; weights >= 0)
}

// ---------------- K1: channel sum + bit-pack mask ----------------
__global__ __launch_bounds__(256) void k_prep(const float* __restrict__ t,
                                              uint8_t* __restrict__ chsum,
                                              uint32_t* __restrict__ bits) {
  int p = blockIdx.x * 256 + threadIdx.x;
  float s = t[p] + t[p + NPIX] + t[p + 2 * NPIX] + t[p + 3 * NPIX] + t[p + 4 * NPIX];
  int c = (int)s;  // 0..5 exactly
  chsum[p] = (uint8_t)c;
  unsigned long long m = __ballot(c > 0);
  int lane = threadIdx.x & 63;
  if (lane == 0)       bits[p >> 5] = (uint32_t)m;
  else if (lane == 32) bits[p >> 5] = (uint32_t)(m >> 32);
}

// ---------------- K2: bit-parallel contour + weights + global min/max ----------------
__global__ __launch_bounds__(256) void k_contour(const uint32_t* __restrict__ bits,
                                                 const uint8_t* __restrict__ chsum,
                                                 float* __restrict__ wout,
                                                 unsigned* __restrict__ minmax) {
  __shared__ float tab[16];
  __shared__ float stage[256 * 32];  // 32 KiB staging for coalesced writes

  if (threadIdx.x < 16) {
    float v = 0.0f;
    if (threadIdx.x < 14) {
      float d = sqrtf((float)c_d2s[threadIdx.x]);
      v = 1.0f / (d + 1e-10f);  // contour value: 1/min_d
    }
    tab[threadIdx.x] = v;  // tab[14]=tab[15]=0 (no differing neighbor)
  }
  __syncthreads();

  int tid = blockIdx.x * 256 + threadIdx.x;
  int y  = tid >> 6;   // row
  int wx = tid & 63;   // word within row

  uint32_t rowP[9], rowC[9], rowN[9];
#pragma unroll
  for (int dy = 0; dy < 9; ++dy) {
    int yy = y + dy - 4;
    yy = yy < 0 ? 0 : (yy > HH - 1 ? HH - 1 : yy);
    const uint32_t* r = bits + yy * WPR;
    uint32_t cur = r[wx];
    uint32_t prev = (wx > 0)       ? r[wx - 1] : ((cur & 1u) ? 0xFFFFFFFFu : 0u);
    uint32_t next = (wx < WPR - 1) ? r[wx + 1] : ((cur >> 31) ? 0xFFFFFFFFu : 0u);
    rowP[dy] = prev; rowC[dy] = cur; rowN[dy] = next;
  }
  uint32_t W0 = rowC[4];  // center row word (each pixel's own mask bit)

  uint32_t B[14];
#pragma unroll
  for (int g = 0; g < 14; ++g) B[g] = 0u;

#pragma unroll
  for (int dy = 0; dy < 9; ++dy) {
#pragma unroll
    for (int dx = -4; dx <= 4; ++dx) {
      if (dy == 4 && dx == 0) continue;
      const int ddy = dy - 4;
      const int d2 = ddy * ddy + dx * dx;
      const int g = g_of(d2);
      uint32_t s;
      if (dx > 0)      s = (rowC[dy] >> dx) | (rowN[dy] << (32 - dx));
      else if (dx < 0) s = (rowC[dy] << (-dx)) | (rowP[dy] >> (32 + dx));
      else             s = rowC[dy];
      B[g] |= s ^ W0;  // bit set where neighbor differs from center
    }
  }

  // resolve min-distance group per pixel via bit-planes (ascending d2)
  uint32_t R = 0u, p0 = 0u, p1 = 0u, p2 = 0u, p3 = 0u;
#pragma unroll
  for (int g = 0; g < 14; ++g) {
    uint32_t nw = B[g] & ~R;
    R |= nw;
    if (g & 1) p0 |= nw;
    if (g & 2) p1 |= nw;
    if (g & 4) p2 |= nw;
    if (g & 8) p3 |= nw;
  }
  uint32_t un = ~R;  // unresolved -> g = 14 (0b1110) -> contour 0
  p1 |= un; p2 |= un; p3 |= un;

  // chsum bytes for this word's 32 pixels
  const uint4* cs4 = (const uint4*)(chsum + y * WW + wx * 32);
  uint4 ca = cs4[0], cb = cs4[1];
  uint32_t comp[8] = {ca.x, ca.y, ca.z, ca.w, cb.x, cb.y, cb.z, cb.w};

  float lmin = 3.4e38f, lmax = 0.0f;
  const int tix = threadIdx.x;
#pragma unroll
  for (int i = 0; i < 32; ++i) {
    int g = ((p0 >> i) & 1) | (((p1 >> i) & 1) << 1) | (((p2 >> i) & 1) << 2) |
            (((p3 >> i) & 1) << 3);
    float contour = tab[g];
    float ch = (float)((comp[i >> 2] >> ((i & 3) * 8)) & 0xFFu);
    float wv = ch + contour;
    wv = wv * wv;
    lmin = fminf(lmin, wv);
    lmax = fmaxf(lmax, wv);
    stage[tix * 32 + ((i + tix) & 31)] = wv;  // swizzled: conflict-free
  }

  // wave reduce min/max, one atomic pair per wave (float bits order as uint for >=0)
#pragma unroll
  for (int off = 1; off < 64; off <<= 1) {
    lmin = fminf(lmin, __shfl_xor(lmin, off));
    lmax = fmaxf(lmax, __shfl_xor(lmax, off));
  }
  if ((tix & 63) == 0) {
    atomicMin(&minmax[0], __float_as_uint(lmin));
    atomicMax(&minmax[1], __float_as_uint(lmax));
  }

  __syncthreads();
  // coalesced write-out: block covers 4 full rows (8192 floats)
  int y0 = blockIdx.x * 4;
  float* outbase = wout + y0 * WW;
#pragma unroll
  for (int k = 0; k < 32; ++k) {
    int q = k * 256 + tix;      // 0..8191
    int r = q >> 11;            // row within block
    int x = q & 2047;           // column
    int tsrc = r * 64 + (x >> 5);
    int e = x & 31;
    outbase[q] = stage[tsrc * 32 + ((e + tsrc) & 31)];
  }
}

// ---------------- K3: normalize + mask ----------------
__global__ __launch_bounds__(256) void k_norm(const uint32_t* __restrict__ bits,
                                              const unsigned* __restrict__ minmax,
                                              float* __restrict__ out) {
  int p4 = blockIdx.x * 256 + threadIdx.x;  // handles 4 pixels
  float mn = __uint_as_float(minmax[0]);
  float mx = __uint_as_float(minmax[1]);
  float inv = 1.0f / (mx - mn + 1e-10f);
  float4 v = ((float4*)out)[p4];
  int pix = p4 * 4;
  uint32_t wbits = bits[pix >> 5] >> (pix & 31);
  v.x = (wbits & 1u) ? (v.x - mn) * inv : 0.0f;
  v.y = (wbits & 2u) ? (v.y - mn) * inv : 0.0f;
  v.z = (wbits & 4u) ? (v.z - mn) * inv : 0.0f;
  v.w = (wbits & 8u) ? (v.w - mn) * inv : 0.0f;
  ((float4*)out)[p4] = v;
}

extern "C" void kernel_launch(void* const* d_in, const int* in_sizes, int n_in,
                              void* d_out, int out_size, void* d_ws, size_t ws_size,
                              hipStream_t stream) {
  const float* target = (const float*)d_in[0];
  uint8_t* chsum = (uint8_t*)d_ws;
  uint32_t* bits = (uint32_t*)((char*)d_ws + (4u << 20));
  unsigned* minmax = (unsigned*)((char*)d_ws + (4u << 20) + (512u << 10));
  float* out = (float*)d_out;

  k_init<<<1, 1, 0, stream>>>(minmax);
  k_prep<<<NPIX / 256, 256, 0, stream>>>(target, chsum, bits);
  k_contour<<<(HH * WPR) / 256, 256, 0, stream>>>(bits, chsum, out, minmax);
  k_norm<<<(NPIX / 4) / 256, 256, 0, stream>>>(bits, minmax, out);
}

// Round 2
// 82.210 us; speedup vs baseline: 1.0636x; 1.0636x over previous
//
#include <hip/hip_runtime.h>
#include <stdint.h>

#define HH 2048
#define WW 2048
#define NPIX (HH * WW)
#define WPR (WW / 32)   // 64 words per row

// distinct squared distances in the 9x9 window (sorted ascending)
__device__ __constant__ int c_d2s[14] = {1, 2, 4, 5, 8, 9, 10, 13, 16, 17, 18, 20, 25, 32};

__host__ __device__ constexpr int g_of(int d2) {
  switch (d2) {
    case 1:  return 0;  case 2:  return 1;  case 4:  return 2;  case 5:  return 3;
    case 8:  return 4;  case 9:  return 5;  case 10: return 6;  case 13: return 7;
    case 16: return 8;  case 17: return 9;  case 18: return 10; case 20: return 11;
    case 25: return 12; case 32: return 13;
  }
  return 15;
}

// ---------------- K0: init min/max ----------------
__global__ void k_init(unsigned* minmax) {
  minmax[0] = 0x7f800000u;  // +inf (min accumulator)
  minmax[1] = 0u;           // 0    (max accumulator; weights >= 0)
}

// ---------------- K1: channel sum + bit-pack mask (8 px/thread) ----------------
__global__ __launch_bounds__(256) void k_prep(const float* __restrict__ t,
                                              uint8_t* __restrict__ chsum,
                                              uint8_t* __restrict__ bits8) {
  int p = blockIdx.x * 256 + threadIdx.x;  // handles pixels 8p..8p+7
  const float4* t4 = (const float4*)t;
  float s[8] = {0, 0, 0, 0, 0, 0, 0, 0};
#pragma unroll
  for (int ch = 0; ch < 5; ++ch) {
    const float4* base = t4 + (size_t)ch * (NPIX / 4) + 2 * (size_t)p;
    float4 a = base[0], b = base[1];
    s[0] += a.x; s[1] += a.y; s[2] += a.z; s[3] += a.w;
    s[4] += b.x; s[5] += b.y; s[6] += b.z; s[7] += b.w;
  }
  uint32_t lo = 0, hi = 0, mb = 0;
#pragma unroll
  for (int i = 0; i < 8; ++i) {
    uint32_t c = (uint32_t)s[i];  // 0..5 exactly
    if (i < 4) lo |= c << (8 * i);
    else       hi |= c << (8 * (i - 4));
    mb |= (c > 0 ? 1u : 0u) << i;
  }
  ((uint2*)chsum)[p] = make_uint2(lo, hi);
  bits8[p] = (uint8_t)mb;
}

// ---------------- K2: bit-parallel contour -> code bytes + global min/max ----------------
// codes buffer doubles as chsum input: each thread reads its own 32 chsum bytes,
// then overwrites them with code bytes (c | g<<3). No cross-thread overlap.
__global__ __launch_bounds__(256) void k_contour(const uint32_t* __restrict__ bits,
                                                 uint8_t* codes,
                                                 unsigned* __restrict__ minmax) {
  __shared__ float tab[16];
  if (threadIdx.x < 16) {
    float v = 0.0f;
    if (threadIdx.x < 14) {
      float d = sqrtf((float)c_d2s[threadIdx.x]);
      v = 1.0f / (d + 1e-10f);  // contour value: 1/min_d
    }
    tab[threadIdx.x] = v;  // tab[14]=tab[15]=0 (no differing neighbor)
  }
  __syncthreads();

  int tid = blockIdx.x * 256 + threadIdx.x;
  int y  = tid >> 6;   // row
  int wx = tid & 63;   // word within row

  uint32_t rowP[9], rowC[9], rowN[9];
#pragma unroll
  for (int dy = 0; dy < 9; ++dy) {
    int yy = y + dy - 4;
    yy = yy < 0 ? 0 : (yy > HH - 1 ? HH - 1 : yy);
    const uint32_t* r = bits + yy * WPR;
    uint32_t cur = r[wx];
    uint32_t prev = (wx > 0)       ? r[wx - 1] : ((cur & 1u) ? 0xFFFFFFFFu : 0u);
    uint32_t next = (wx < WPR - 1) ? r[wx + 1] : ((cur >> 31) ? 0xFFFFFFFFu : 0u);
    rowP[dy] = prev; rowC[dy] = cur; rowN[dy] = next;
  }
  uint32_t W0 = rowC[4];  // center row word (each pixel's own mask bit)

  uint32_t B[14];
#pragma unroll
  for (int g = 0; g < 14; ++g) B[g] = 0u;

#pragma unroll
  for (int dy = 0; dy < 9; ++dy) {
#pragma unroll
    for (int dx = -4; dx <= 4; ++dx) {
      if (dy == 4 && dx == 0) continue;
      const int ddy = dy - 4;
      const int d2 = ddy * ddy + dx * dx;
      const int g = g_of(d2);
      uint32_t s;
      if (dx > 0)      s = (rowC[dy] >> dx) | (rowN[dy] << (32 - dx));
      else if (dx < 0) s = (rowC[dy] << (-dx)) | (rowP[dy] >> (32 + dx));
      else             s = rowC[dy];
      B[g] |= s ^ W0;  // bit set where neighbor differs from center
    }
  }

  // resolve min-distance group per pixel via bit-planes (ascending d2)
  uint32_t R = 0u, p0 = 0u, p1 = 0u, p2 = 0u, p3 = 0u;
#pragma unroll
  for (int g = 0; g < 14; ++g) {
    uint32_t nw = B[g] & ~R;
    R |= nw;
    if (g & 1) p0 |= nw;
    if (g & 2) p1 |= nw;
    if (g & 4) p2 |= nw;
    if (g & 8) p3 |= nw;
  }
  uint32_t un = ~R;  // unresolved -> g = 14 (0b1110) -> contour 0
  p1 |= un; p2 |= un; p3 |= un;

  // chsum bytes for this word's 32 pixels
  const uint4* cs4 = (const uint4*)(codes + y * WW + wx * 32);
  uint4 ca = cs4[0], cb = cs4[1];
  uint32_t comp[8] = {ca.x, ca.y, ca.z, ca.w, cb.x, cb.y, cb.z, cb.w};

  uint32_t cw[8];
  float lmin = 3.4e38f, lmax = 0.0f;
#pragma unroll
  for (int i = 0; i < 32; ++i) {
    uint32_t g = ((p0 >> i) & 1) | (((p1 >> i) & 1) << 1) | (((p2 >> i) & 1) << 2) |
                 (((p3 >> i) & 1) << 3);
    uint32_t c = (comp[i >> 2] >> ((i & 3) * 8)) & 0xFFu;
    float wv = (float)c + tab[g];
    wv = wv * wv;
    lmin = fminf(lmin, wv);
    lmax = fmaxf(lmax, wv);
    uint32_t code = c | (g << 3);
    if ((i & 3) == 0) cw[i >> 2] = code;
    else              cw[i >> 2] |= code << ((i & 3) * 8);
  }

  // wave reduce min/max, one atomic pair per wave (float bits order as uint for >=0)
#pragma unroll
  for (int off = 1; off < 64; off <<= 1) {
    lmin = fminf(lmin, __shfl_xor(lmin, off));
    lmax = fmaxf(lmax, __shfl_xor(lmax, off));
  }
  if ((threadIdx.x & 63) == 0) {
    atomicMin(&minmax[0], __float_as_uint(lmin));
    atomicMax(&minmax[1], __float_as_uint(lmax));
  }

  // write code bytes over the chsum region (same 32 bytes this thread read)
  uint4* co4 = (uint4*)(codes + y * WW + wx * 32);
  co4[0] = make_uint4(cw[0], cw[1], cw[2], cw[3]);
  co4[1] = make_uint4(cw[4], cw[5], cw[6], cw[7]);
}

// ---------------- K3: LUT normalize + mask (4 px/thread) ----------------
__global__ __launch_bounds__(256) void k_norm(const uint8_t* __restrict__ codes,
                                              const unsigned* __restrict__ minmax,
                                              float* __restrict__ out) {
  __shared__ float lut[128];
  int tix = threadIdx.x;
  if (tix < 128) {
    float mn = __uint_as_float(minmax[0]);
    float mx = __uint_as_float(minmax[1]);
    float inv = 1.0f / (mx - mn + 1e-10f);
    int c = tix & 7;   // 0..5 used
    int g = tix >> 3;  // 0..15
    float contour = 0.0f;
    if (g < 14) contour = 1.0f / (sqrtf((float)c_d2s[g]) + 1e-10f);
    float wv = (float)c + contour;
    wv = wv * wv;
    lut[tix] = (c > 0) ? (wv - mn) * inv : 0.0f;
  }
  __syncthreads();

  int p = blockIdx.x * 256 + threadIdx.x;  // handles 4 pixels
  uint32_t cwv = ((const uint32_t*)codes)[p];
  float4 v = make_float4(lut[cwv & 127], lut[(cwv >> 8) & 127],
                         lut[(cwv >> 16) & 127], lut[(cwv >> 24) & 127]);
  ((float4*)out)[p] = v;
}

extern "C" void kernel_launch(void* const* d_in, const int* in_sizes, int n_in,
                              void* d_out, int out_size, void* d_ws, size_t ws_size,
                              hipStream_t stream) {
  const float* target = (const float*)d_in[0];
  uint8_t* codes = (uint8_t*)d_ws;                              // chsum -> codes, 4 MB
  uint8_t* bits8 = (uint8_t*)d_ws + (4u << 20);                 // 512 KB packed mask
  unsigned* minmax = (unsigned*)((char*)d_ws + (4u << 20) + (512u << 10));
  float* out = (float*)d_out;

  k_init<<<1, 1, 0, stream>>>(minmax);
  k_prep<<<NPIX / 8 / 256, 256, 0, stream>>>(target, codes, bits8);
  k_contour<<<(HH * WPR) / 256, 256, 0, stream>>>((const uint32_t*)bits8, codes, minmax);
  k_norm<<<(NPIX / 4) / 256, 256, 0, stream>>>(codes, minmax, out);
}

// Round 3
// 35.642 us; speedup vs baseline: 2.4533x; 2.3066x over previous
//
#include <hip/hip_runtime.h>
#include <stdint.h>

#define HH 2048
#define WW 2048
#define NPIX (HH * WW)
#define WPR (WW / 32)   // 64 words per row
#define NBLK 512        // k_contour grid

// distinct squared distances in the 9x9 window (sorted ascending)
__device__ __constant__ int c_d2s[14] = {1, 2, 4, 5, 8, 9, 10, 13, 16, 17, 18, 20, 25, 32};

__host__ __device__ constexpr int g_of(int d2) {
  switch (d2) {
    case 1:  return 0;  case 2:  return 1;  case 4:  return 2;  case 5:  return 3;
    case 8:  return 4;  case 9:  return 5;  case 10: return 6;  case 13: return 7;
    case 16: return 8;  case 17: return 9;  case 18: return 10; case 20: return 11;
    case 25: return 12; case 32: return 13;
  }
  return 15;
}

// ---------------- K1: channel sum + bit-pack mask (8 px/thread) ----------------
__global__ __launch_bounds__(256) void k_prep(const float* __restrict__ t,
                                              uint8_t* __restrict__ chsum,
                                              uint8_t* __restrict__ bits8) {
  int p = blockIdx.x * 256 + threadIdx.x;  // handles pixels 8p..8p+7
  const float4* t4 = (const float4*)t;
  float s[8] = {0, 0, 0, 0, 0, 0, 0, 0};
#pragma unroll
  for (int ch = 0; ch < 5; ++ch) {
    const float4* base = t4 + (size_t)ch * (NPIX / 4) + 2 * (size_t)p;
    float4 a = base[0], b = base[1];
    s[0] += a.x; s[1] += a.y; s[2] += a.z; s[3] += a.w;
    s[4] += b.x; s[5] += b.y; s[6] += b.z; s[7] += b.w;
  }
  uint32_t lo = 0, hi = 0, mb = 0;
#pragma unroll
  for (int i = 0; i < 8; ++i) {
    uint32_t c = (uint32_t)s[i];  // 0..5 exactly
    if (i < 4) lo |= c << (8 * i);
    else       hi |= c << (8 * (i - 4));
    mb |= (c > 0 ? 1u : 0u) << i;
  }
  ((uint2*)chsum)[p] = make_uint2(lo, hi);
  bits8[p] = (uint8_t)mb;
}

// ---------------- K2: bit-parallel contour -> code bytes + per-block min/max ----------------
// codes buffer doubles as chsum input: each thread reads its own 32 chsum bytes,
// then overwrites them with code bytes (c | g<<3). No cross-thread overlap.
__global__ __launch_bounds__(256) void k_contour(const uint32_t* __restrict__ bits,
                                                 uint8_t* codes,
                                                 float2* __restrict__ blockred) {
  __shared__ float tab[16];
  __shared__ float red[8];
  if (threadIdx.x < 16) {
    float v = 0.0f;
    if (threadIdx.x < 14) {
      float d = sqrtf((float)c_d2s[threadIdx.x]);
      v = 1.0f / (d + 1e-10f);  // contour value: 1/min_d
    }
    tab[threadIdx.x] = v;  // tab[14]=tab[15]=0 (no differing neighbor)
  }
  __syncthreads();

  int tid = blockIdx.x * 256 + threadIdx.x;
  int y  = tid >> 6;   // row
  int wx = tid & 63;   // word within row

  uint32_t rowP[9], rowC[9], rowN[9];
#pragma unroll
  for (int dy = 0; dy < 9; ++dy) {
    int yy = y + dy - 4;
    yy = yy < 0 ? 0 : (yy > HH - 1 ? HH - 1 : yy);
    const uint32_t* r = bits + yy * WPR;
    uint32_t cur = r[wx];
    uint32_t prev = (wx > 0)       ? r[wx - 1] : ((cur & 1u) ? 0xFFFFFFFFu : 0u);
    uint32_t next = (wx < WPR - 1) ? r[wx + 1] : ((cur >> 31) ? 0xFFFFFFFFu : 0u);
    rowP[dy] = prev; rowC[dy] = cur; rowN[dy] = next;
  }
  uint32_t W0 = rowC[4];  // center row word (each pixel's own mask bit)

  uint32_t B[14];
#pragma unroll
  for (int g = 0; g < 14; ++g) B[g] = 0u;

#pragma unroll
  for (int dy = 0; dy < 9; ++dy) {
#pragma unroll
    for (int dx = -4; dx <= 4; ++dx) {
      if (dy == 4 && dx == 0) continue;
      const int ddy = dy - 4;
      const int d2 = ddy * ddy + dx * dx;
      const int g = g_of(d2);
      uint32_t s;
      if (dx > 0)      s = (rowC[dy] >> dx) | (rowN[dy] << (32 - dx));
      else if (dx < 0) s = (rowC[dy] << (-dx)) | (rowP[dy] >> (32 + dx));
      else             s = rowC[dy];
      B[g] |= s ^ W0;  // bit set where neighbor differs from center
    }
  }

  // resolve min-distance group per pixel via bit-planes (ascending d2)
  uint32_t R = 0u, p0 = 0u, p1 = 0u, p2 = 0u, p3 = 0u;
#pragma unroll
  for (int g = 0; g < 14; ++g) {
    uint32_t nw = B[g] & ~R;
    R |= nw;
    if (g & 1) p0 |= nw;
    if (g & 2) p1 |= nw;
    if (g & 4) p2 |= nw;
    if (g & 8) p3 |= nw;
  }
  uint32_t un = ~R;  // unresolved -> g = 14 (0b1110) -> contour 0
  p1 |= un; p2 |= un; p3 |= un;

  // chsum bytes for this word's 32 pixels
  const uint4* cs4 = (const uint4*)(codes + y * WW + wx * 32);
  uint4 ca = cs4[0], cb = cs4[1];
  uint32_t comp[8] = {ca.x, ca.y, ca.z, ca.w, cb.x, cb.y, cb.z, cb.w};

  uint32_t cw[8];
  float lmin = 3.4e38f, lmax = 0.0f;
#pragma unroll
  for (int i = 0; i < 32; ++i) {
    uint32_t g = ((p0 >> i) & 1) | (((p1 >> i) & 1) << 1) | (((p2 >> i) & 1) << 2) |
                 (((p3 >> i) & 1) << 3);
    uint32_t c = (comp[i >> 2] >> ((i & 3) * 8)) & 0xFFu;
    float wv = (float)c + tab[g];
    wv = wv * wv;
    lmin = fminf(lmin, wv);
    lmax = fmaxf(lmax, wv);
    uint32_t code = c | (g << 3);
    if ((i & 3) == 0) cw[i >> 2] = code;
    else              cw[i >> 2] |= code << ((i & 3) * 8);
  }

  // write code bytes over the chsum region (same 32 bytes this thread read)
  uint4* co4 = (uint4*)(codes + y * WW + wx * 32);
  co4[0] = make_uint4(cw[0], cw[1], cw[2], cw[3]);
  co4[1] = make_uint4(cw[4], cw[5], cw[6], cw[7]);

  // wave reduce min/max, then block reduce, ONE store per block (no atomics)
#pragma unroll
  for (int off = 1; off < 64; off <<= 1) {
    lmin = fminf(lmin, __shfl_xor(lmin, off));
    lmax = fmaxf(lmax, __shfl_xor(lmax, off));
  }
  int wv = threadIdx.x >> 6;
  if ((threadIdx.x & 63) == 0) { red[wv] = lmin; red[wv + 4] = lmax; }
  __syncthreads();
  if (threadIdx.x == 0) {
    float mn = fminf(fminf(red[0], red[1]), fminf(red[2], red[3]));
    float mx = fmaxf(fmaxf(red[4], red[5]), fmaxf(red[6], red[7]));
    blockred[blockIdx.x] = make_float2(mn, mx);
  }
}

// ---------------- K2b: fold 512 per-block pairs into minmax ----------------
__global__ __launch_bounds__(256) void k_reduce(const float2* __restrict__ br,
                                                unsigned* __restrict__ minmax) {
  __shared__ float s[8];
  int t = threadIdx.x;
  float2 a = br[t], b = br[t + 256];
  float mn = fminf(a.x, b.x), mx = fmaxf(a.y, b.y);
#pragma unroll
  for (int off = 1; off < 64; off <<= 1) {
    mn = fminf(mn, __shfl_xor(mn, off));
    mx = fmaxf(mx, __shfl_xor(mx, off));
  }
  int wv = t >> 6;
  if ((t & 63) == 0) { s[wv] = mn; s[wv + 4] = mx; }
  __syncthreads();
  if (t == 0) {
    mn = fminf(fminf(s[0], s[1]), fminf(s[2], s[3]));
    mx = fmaxf(fmaxf(s[4], s[5]), fmaxf(s[6], s[7]));
    minmax[0] = __float_as_uint(mn);
    minmax[1] = __float_as_uint(mx);
  }
}

// ---------------- K3: LUT normalize + mask (4 px/thread) ----------------
__global__ __launch_bounds__(256) void k_norm(const uint8_t* __restrict__ codes,
                                              const unsigned* __restrict__ minmax,
                                              float* __restrict__ out) {
  __shared__ float lut[128];
  int tix = threadIdx.x;
  if (tix < 128) {
    float mn = __uint_as_float(minmax[0]);
    float mx = __uint_as_float(minmax[1]);
    float inv = 1.0f / (mx - mn + 1e-10f);
    int c = tix & 7;   // 0..5 used
    int g = tix >> 3;  // 0..15
    float contour = 0.0f;
    if (g < 14) contour = 1.0f / (sqrtf((float)c_d2s[g]) + 1e-10f);
    float wv = (float)c + contour;
    wv = wv * wv;
    lut[tix] = (c > 0) ? (wv - mn) * inv : 0.0f;
  }
  __syncthreads();

  int p = blockIdx.x * 256 + threadIdx.x;  // handles 4 pixels
  uint32_t cwv = ((const uint32_t*)codes)[p];
  float4 v = make_float4(lut[cwv & 127], lut[(cwv >> 8) & 127],
                         lut[(cwv >> 16) & 127], lut[(cwv >> 24) & 127]);
  ((float4*)out)[p] = v;
}

extern "C" void kernel_launch(void* const* d_in, const int* in_sizes, int n_in,
                              void* d_out, int out_size, void* d_ws, size_t ws_size,
                              hipStream_t stream) {
  const float* target = (const float*)d_in[0];
  uint8_t* codes = (uint8_t*)d_ws;                               // chsum -> codes, 4 MB
  uint8_t* bits8 = (uint8_t*)d_ws + (4u << 20);                  // 512 KB packed mask
  float2* blockred = (float2*)((char*)d_ws + (4u << 20) + (512u << 10));  // 4 KB
  unsigned* minmax = (unsigned*)((char*)blockred + NBLK * sizeof(float2));

  float* out = (float*)d_out;

  k_prep<<<NPIX / 8 / 256, 256, 0, stream>>>(target, codes, bits8);
  k_contour<<<NBLK, 256, 0, stream>>>((const uint32_t*)bits8, codes, blockred);
  k_reduce<<<1, 256, 0, stream>>>(blockred, minmax);
  k_norm<<<(NPIX / 4) / 256, 256, 0, stream>>>(codes, minmax, out);
}